// Round 9
// baseline (168.949 us; speedup 1.0000x reference)
//
#include <hip/hip_runtime.h>
#include <stdint.h>

#define B_ROWS 4096
#define D_IN   2048
#define D_OUT  2048
#define KANCH  4

typedef _Float16 half8  __attribute__((ext_vector_type(8)));
typedef _Float16 half4  __attribute__((ext_vector_type(4)));
typedef float    floatx4 __attribute__((ext_vector_type(4)));
typedef const __attribute__((address_space(1))) uint8_t* gptr_t;
typedef __attribute__((address_space(3))) uint8_t* lptr_t;

__device__ __forceinline__ float frcp(float x)   { return __builtin_amdgcn_rcpf(x); }
__device__ __forceinline__ float ftanh(float x)  { float e = __expf(2.f * x); return (e - 1.f) * frcp(e + 1.f); }
__device__ __forceinline__ float fatanh(float z) { return 0.5f * __logf((1.f + z) * frcp(1.f - z)); }

// K1 fused prep (R8: 16B half8 stores on both conversion streams):
//  blocks [0,1024): x->fp16 (contiguous-8 per lane), n2x, softplus partial
//  blocks [1024,2048): W->fp16 (contiguous-8 per lane)
//  block 2048: static dots  scal[1]=b.b, scal[2+k]=b.a_k, scal[6+k]=a_k.a_k
__global__ __launch_bounds__(256) void k_prep(
    const float* __restrict__ x,
    const float* __restrict__ W,
    const float* __restrict__ cw,
    const float* __restrict__ cb,
    const float* __restrict__ bias,
    const float* __restrict__ anchors,
    _Float16* __restrict__ xh,
    _Float16* __restrict__ Wh,
    float* __restrict__ n2x,
    float* __restrict__ spart,
    float* __restrict__ scal)
{
    int tid = threadIdx.x;
    if (blockIdx.x < 1024) {
        int w = tid >> 6, lane = tid & 63;
        int row = blockIdx.x * 4 + w;
        const float* xr = x + (size_t)row * D_IN;
        _Float16* xo = xh + (size_t)row * D_IN;
        float dot = 0.f, ss = 0.f;
#pragma unroll
        for (int i = 0; i < 4; ++i) {
            int base = i * 512 + lane * 8;           // 8 contiguous floats/lane
            floatx4 a = *(const floatx4*)(xr + base);
            floatx4 b = *(const floatx4*)(xr + base + 4);
            floatx4 wa = *(const floatx4*)(cw + base);
            floatx4 wb = *(const floatx4*)(cw + base + 4);
#pragma unroll
            for (int j = 0; j < 4; ++j) {
                dot += a[j] * wa[j] + b[j] * wb[j];
                ss  += a[j] * a[j] + b[j] * b[j];
            }
            half8 h = {(_Float16)a[0], (_Float16)a[1], (_Float16)a[2], (_Float16)a[3],
                       (_Float16)b[0], (_Float16)b[1], (_Float16)b[2], (_Float16)b[3]};
            *(half8*)(xo + base) = h;                // 16B store
        }
#pragma unroll
        for (int off = 32; off; off >>= 1) {
            dot += __shfl_down(dot, off);
            ss  += __shfl_down(ss, off);
        }
        __shared__ float spw[4];
        if (lane == 0) {
            n2x[row] = ss;
            float z = dot + cb[0];
            spw[w] = (z > 20.f) ? z : log1pf(expf(z));
        }
        __syncthreads();
        if (tid == 0)
            spart[blockIdx.x] = spw[0] + spw[1] + spw[2] + spw[3];
    } else if (blockIdx.x < 2048) {
        int blk = blockIdx.x - 1024;
        const float* Wp = W + (size_t)blk * 4096;    // 2 rows per block
        _Float16* Wo = Wh + (size_t)blk * 4096;
#pragma unroll
        for (int i = 0; i < 2; ++i) {
            int base = i * 2048 + tid * 8;           // 8 contiguous floats/lane
            floatx4 a = *(const floatx4*)(Wp + base);
            floatx4 b = *(const floatx4*)(Wp + base + 4);
            half8 h = {(_Float16)a[0], (_Float16)a[1], (_Float16)a[2], (_Float16)a[3],
                       (_Float16)b[0], (_Float16)b[1], (_Float16)b[2], (_Float16)b[3]};
            *(half8*)(Wo + base) = h;                // 16B store
        }
    } else {
        // static dots: 9 quantities over D_OUT
        int w = tid >> 6, lane = tid & 63;
        float bf[8], af[KANCH][8];
        *(floatx4*)(bf)     = *(const floatx4*)(bias + tid * 8);
        *(floatx4*)(bf + 4) = *(const floatx4*)(bias + tid * 8 + 4);
#pragma unroll
        for (int k = 0; k < KANCH; ++k) {
            *(floatx4*)(af[k])     = *(const floatx4*)(anchors + (size_t)k * D_OUT + tid * 8);
            *(floatx4*)(af[k] + 4) = *(const floatx4*)(anchors + (size_t)k * D_OUT + tid * 8 + 4);
        }
        float v[9];
#pragma unroll
        for (int q = 0; q < 9; ++q) v[q] = 0.f;
#pragma unroll
        for (int j = 0; j < 8; ++j) {
            v[0] += bf[j] * bf[j];
#pragma unroll
            for (int k = 0; k < KANCH; ++k) {
                v[1 + k] += bf[j] * af[k][j];
                v[5 + k] += af[k][j] * af[k][j];
            }
        }
#pragma unroll
        for (int off = 32; off; off >>= 1)
#pragma unroll
            for (int q = 0; q < 9; ++q) v[q] += __shfl_down(v[q], off);
        __shared__ float red[4][9];
        if (lane == 0)
#pragma unroll
            for (int q = 0; q < 9; ++q) red[w][q] = v[q];
        __syncthreads();
        if (tid == 0)
#pragma unroll
            for (int q = 0; q < 9; ++q)
                scal[1 + q] = red[0][q] + red[1][q] + red[2][q] + red[3][q];
    }
}

// K2 (R9): P = xh @ Wh^T, full K=2048, fp16 out.
// ISOLATES BARRIER COUNT: 256x128 tile, BK=64, TRIPLE-buffered LDS (3x48KB) ->
// exactly ONE raw s_barrier per K-tile (vs 4-8 in the R6 band). vmcnt(6)
// counted once per tile (two 6-load stage groups in flight). No sched pinning:
// all 16 ds_read_b128 issue before the 32 MFMAs; compiler emits counted lgkm
// waits so early MFMAs start at lgkmcnt(8) while later reads are in flight.
// Race safety at 1 barrier/tile: stage(T+2) is issued AFTER tile-T's barrier;
// every wave's tile-(T-1) reads completed before it reached that barrier
// (its lgkm waits precede its MFMA clusters precede the barrier), so
// overwriting buf (T+2)%3 == (T-1)%3 is safe with <=1-tile skew.
// Conflict-free LDS by construction: linear dest tid*16; per-lane global
// source puts lane l's fragment chunk at byte l*16 of each 1KB rowblock.
// No z-split: NT=32 amortizes prologue 2x; P1 eliminated (-33.6MB traffic).
__global__ __launch_bounds__(512) void k_gemm(
    const _Float16* __restrict__ A,
    const _Float16* __restrict__ W,
    _Float16* __restrict__ P)
{
    constexpr int NT = D_IN / 64;                    // 32
    // per buf (48KB): A kh0 [0,16K) kh1 [16K,32K); B kh0 [32K,40K) kh1 [40K,48K)
    __shared__ __align__(16) _Float16 lds[3][24576];
    const int tid  = threadIdx.x;
    const int lane = tid & 63;
    const int w    = tid >> 6;
    const int wm   = w >> 1;          // 0..3 -> 64-row M quad
    const int wn   = w & 1;           // 0..1 -> 64-col N half

    // bijective XCD-aware remap: each XCD gets 4 mt x 8 nt contiguous chunk
    int lin = blockIdx.y * gridDim.x + blockIdx.x;   // 0..255
    int xcd = lin & 7;
    int i   = lin >> 3;                              // 0..31
    int mt  = (xcd >> 1) * 4 + (i >> 3);             // 0..15 (256-row tiles)
    int nt  = (xcd & 1) * 8 + (i & 7);               // 0..15 (128-col tiles)
    const int bm0 = mt * 256;
    const int bn0 = nt * 128;

    // staging: linear LDS dest tid*16; per-lane global source = fragment perm
    const int e0 = tid * 16;
    const int srow = w * 16 + (lane & 15);
    const int scol = (lane >> 4) * 8;
    const size_t asrc = (size_t)(bm0 + srow) * D_IN + scol;
    const size_t bsrc = (size_t)(bn0 + srow) * D_IN + scol;
    // read offsets: rowblock*1024 + lane*16 (conflict-free: addr = lane*16 + const)
    const int rA = wm * 4096 + lane * 16;            // + kh*16384 + mi*1024
    const int rB = 32768 + wn * 4096 + lane * 16;    // + kh*8192  + ni*1024

#define GLL(SRC, DSTB) __builtin_amdgcn_global_load_lds((gptr_t)(SRC), (lptr_t)(DSTB), 16, 0, 0)
#define STAGE6(BP, KT) do { \
    uint8_t* b_ = (uint8_t*)(BP); \
    size_t ko_ = (size_t)(KT) * 64; \
    GLL(A + asrc + ko_,                        b_ + e0);                 /* A kh0 rows 0-127  */ \
    GLL(A + asrc + (size_t)128 * D_IN + ko_,   b_ + 8192 + e0);          /* A kh0 rows 128-255*/ \
    GLL(A + asrc + ko_ + 32,                   b_ + 16384 + e0);         /* A kh1 rows 0-127  */ \
    GLL(A + asrc + (size_t)128 * D_IN + ko_ + 32, b_ + 24576 + e0);      /* A kh1 rows 128-255*/ \
    GLL(W + bsrc + ko_,                        b_ + 32768 + e0);         /* B kh0             */ \
    GLL(W + bsrc + ko_ + 32,                   b_ + 40960 + e0);         /* B kh1             */ \
} while (0)

    floatx4 acc[4][4];
#pragma unroll
    for (int mi = 0; mi < 4; ++mi)
#pragma unroll
        for (int ni = 0; ni < 4; ++ni)
            acc[mi][ni] = (floatx4){0.f, 0.f, 0.f, 0.f};

    uint8_t* base0 = (uint8_t*)&lds[0][0];
    uint8_t* base1 = (uint8_t*)&lds[1][0];
    uint8_t* base2 = (uint8_t*)&lds[2][0];

    // prologue: tiles 0,1 staged into bufs 0,1
    STAGE6(base0, 0);
    STAGE6(base1, 1);

    uint8_t *p0 = base0, *p1 = base1, *p2 = base2;

#define TILE_READS_MFMA(BP) do { \
    half8 aq0[4], bq0[4], aq1[4], bq1[4]; \
    const uint8_t* b_ = (const uint8_t*)(BP); \
    _Pragma("unroll") for (int mi = 0; mi < 4; ++mi) \
        aq0[mi] = *(const half8*)(b_ + rA + mi * 1024); \
    _Pragma("unroll") for (int ni = 0; ni < 4; ++ni) \
        bq0[ni] = *(const half8*)(b_ + rB + ni * 1024); \
    _Pragma("unroll") for (int mi = 0; mi < 4; ++mi) \
        aq1[mi] = *(const half8*)(b_ + 16384 + rA + mi * 1024); \
    _Pragma("unroll") for (int ni = 0; ni < 4; ++ni) \
        bq1[ni] = *(const half8*)(b_ + 8192 + rB + ni * 1024); \
    __builtin_amdgcn_s_setprio(1); \
    _Pragma("unroll") for (int mi = 0; mi < 4; ++mi) \
    _Pragma("unroll") for (int ni = 0; ni < 4; ++ni) \
        acc[mi][ni] = __builtin_amdgcn_mfma_f32_16x16x32_f16(aq0[mi], bq0[ni], acc[mi][ni], 0, 0, 0); \
    _Pragma("unroll") for (int mi = 0; mi < 4; ++mi) \
    _Pragma("unroll") for (int ni = 0; ni < 4; ++ni) \
        acc[mi][ni] = __builtin_amdgcn_mfma_f32_16x16x32_f16(aq1[mi], bq1[ni], acc[mi][ni], 0, 0, 0); \
    __builtin_amdgcn_s_setprio(0); \
} while (0)

    // main loop: ONE barrier per tile; vmcnt(6) = allow next tile's 6 stages
    for (int T = 0; T < NT - 1; ++T) {
        asm volatile("s_waitcnt vmcnt(6)" ::: "memory");
        __builtin_amdgcn_s_barrier();
        if (T + 2 < NT) STAGE6(p2, T + 2);
        TILE_READS_MFMA(p0);
        uint8_t* tmp = p0; p0 = p1; p1 = p2; p2 = tmp;
    }
    // last tile: drain all stages
    asm volatile("s_waitcnt vmcnt(0)" ::: "memory");
    __builtin_amdgcn_s_barrier();
    TILE_READS_MFMA(p0);

#undef TILE_READS_MFMA
#undef STAGE6
#undef GLL

    // epilogue: fp16 store. C/D layout col=lane&15, row=(lane>>4)*4+r
#pragma unroll
    for (int mi = 0; mi < 4; ++mi) {
#pragma unroll
        for (int r = 0; r < 4; ++r) {
            int gm = bm0 + wm * 64 + mi * 16 + (lane >> 4) * 4 + r;
#pragma unroll
            for (int ni = 0; ni < 4; ++ni) {
                int gn = bn0 + wn * 64 + ni * 16 + (lane & 15);
                P[(size_t)gm * D_OUT + gn] = (_Float16)acc[mi][ni][r];
            }
        }
    }
}

// K3 (R1-verified best): per row b: p = P0[b](+P1[b]); reduce pp,pb,pa_k +
//  spart-sum -> wave-0 Mobius coefficients -> out = cp*p + cb*bias + sum ca_k*a_k
__global__ __launch_bounds__(256) void k_mobius(
    const _Float16* __restrict__ P0,
    const _Float16* __restrict__ P1,
    const float* __restrict__ bias,
    const float* __restrict__ anchors,
    const float* __restrict__ tv,
    const float* __restrict__ aw,
    const float* __restrict__ n2x,
    const float* __restrict__ spart,
    const float* __restrict__ scal,
    int split,
    float* __restrict__ out)
{
    int tid = threadIdx.x, w = tid >> 6, lane = tid & 63;
    size_t rowoff = (size_t)blockIdx.x * D_OUT;
    float pf[8], bf[8];
    {
        half8 p = *(const half8*)(P0 + rowoff + tid * 8);
#pragma unroll
        for (int j = 0; j < 8; ++j) pf[j] = (float)p[j];
    }
    if (split == 2) {
        half8 q = *(const half8*)(P1 + rowoff + tid * 8);
#pragma unroll
        for (int j = 0; j < 8; ++j) pf[j] += (float)q[j];
    }
    *(floatx4*)(bf)     = *(const floatx4*)(bias + tid * 8);
    *(floatx4*)(bf + 4) = *(const floatx4*)(bias + tid * 8 + 4);
    float af[KANCH][8];
#pragma unroll
    for (int k = 0; k < KANCH; ++k) {
        *(floatx4*)(af[k])     = *(const floatx4*)(anchors + (size_t)k * D_OUT + tid * 8);
        *(floatx4*)(af[k] + 4) = *(const floatx4*)(anchors + (size_t)k * D_OUT + tid * 8 + 4);
    }
    // v: 0 pp, 1 pb, 2..5 pa_k, 6 spart partial
    float v[7];
#pragma unroll
    for (int q = 0; q < 7; ++q) v[q] = 0.f;
    {
        floatx4 s4 = ((const floatx4*)spart)[tid];   // 1024 floats, 4 per thread
        v[6] = s4[0] + s4[1] + s4[2] + s4[3];
    }
#pragma unroll
    for (int j = 0; j < 8; ++j) {
        v[0] += pf[j] * pf[j];
        v[1] += pf[j] * bf[j];
#pragma unroll
        for (int k = 0; k < KANCH; ++k) v[2 + k] += pf[j] * af[k][j];
    }
#pragma unroll
    for (int off = 32; off; off >>= 1)
#pragma unroll
        for (int q = 0; q < 7; ++q) v[q] += __shfl_down(v[q], off);
    __shared__ float red[4][7];
    __shared__ float cf[2 + KANCH];   // 0: *p, 1: *bias, 2..: *a_k
    if (lane == 0)
#pragma unroll
        for (int q = 0; q < 7; ++q) red[w][q] = v[q];
    __syncthreads();
    if (w == 0) {
        // all 64 lanes run this; lanes 0..3 own anchor k=lane&3
        int k = lane & 3;
        float pp = red[0][0] + red[1][0] + red[2][0] + red[3][0];
        float pb = red[0][1] + red[1][1] + red[2][1] + red[3][1];
        float pa = red[0][2 + k] + red[1][2 + k] + red[2][2 + k] + red[3][2 + k];
        float spsum = red[0][6] + red[1][6] + red[2][6] + red[3][6];
        float bb = scal[1];
        float ba = scal[2 + k];
        float aa = scal[6 + k];
        float c = spsum * (1.0f / (float)B_ROWS);   // BASE_CURVATURE=1
        float sc = __builtin_amdgcn_sqrtf(c);
        float nx = fmaxf(__builtin_amdgcn_sqrtf(n2x[blockIdx.x]), 1e-6f);
        float ax = sc * nx;
        float zx = fminf(fmaxf(ax, -1.f + 1e-5f), 1.f - 1e-5f);
        float f = fatanh(zx) * frcp(ax);
        float hh = f * f * pp + 2.f * f * pb + bb;
        float ha = f * pa + ba;
        float ek = __expf(aw[k]);
        float se = ek;
        se += __shfl_xor(se, 1);
        se += __shfl_xor(se, 2);
        float wk = ek * frcp(se);
        float nh = fmaxf(__builtin_amdgcn_sqrtf(hh), 1e-6f);
        float snh = sc * nh;
        float gy = ftanh(snh) * frcp(snh);
        float x2 = gy * gy * hh;           // ||y||^2
        float B1 = 1.f - c * x2;
        float y2 = aa;
        float dy = gy * ha;                // dot(y, a_k)
        float A1 = 1.f - 2.f * c * dy + c * y2;
        float den1 = fmaxf(1.f - 2.f * c * dy + c * c * x2 * y2, 1e-6f);
        float rd1 = frcp(den1);
        float al = -A1 * rd1, be = B1 * rd1;         // diff = al*y + be*a
        float nd2 = fmaxf(al * al * x2 + 2.f * al * be * dy + be * be * y2, 0.f);
        float nd = fmaxf(__builtin_amdgcn_sqrtf(nd2), 1e-6f);
        float snd = sc * nd;
        float zc = fminf(fmaxf(snd, -1.f + 1e-5f), 1.f - 1e-5f);
        float s = ftanh(tv[k] * fatanh(zc)) * frcp(snd);  // step = s*diff
        float y2s = s * s * nd2;
        float xys = s * (al * x2 + be * dy);
        float A2 = 1.f + 2.f * c * xys + c * y2s;
        float den2 = fmaxf(1.f + 2.f * c * xys + c * c * x2 * y2s, 1e-6f);
        float rd2 = frcp(den2);
        float Cy  = (A2 + B1 * s * al) * rd2;        // g = Cy*y + Cak*a
        float Cak = (B1 * s * be) * rd2;
        float chk = wk * Cy;
        chk += __shfl_xor(chk, 1);
        chk += __shfl_xor(chk, 2);                   // lanes 0..3: sum_k wk*Cy
        if (lane == 0) {
            float c0 = gy * chk;                     // multiplies h = f*p + bias
            cf[0] = c0 * f;
            cf[1] = c0;
        }
        if (lane < 4) cf[2 + lane] = wk * Cak;
    }
    __syncthreads();
    float cp = cf[0], cb_ = cf[1];
    float o[8];
#pragma unroll
    for (int j = 0; j < 8; ++j) {
        float val = cp * pf[j] + cb_ * bf[j];
#pragma unroll
        for (int k = 0; k < KANCH; ++k) val += cf[2 + k] * af[k][j];
        o[j] = val;
    }
    *(floatx4*)(out + rowoff + tid * 8)     = *(floatx4*)(o);
    *(floatx4*)(out + rowoff + tid * 8 + 4) = *(floatx4*)(o + 4);
}

extern "C" void kernel_launch(void* const* d_in, const int* in_sizes, int n_in,
                              void* d_out, int out_size, void* d_ws, size_t ws_size,
                              hipStream_t stream) {
    const float* x       = (const float*)d_in[0];
    const float* wt      = (const float*)d_in[1];
    const float* bias    = (const float*)d_in[2];
    const float* cw      = (const float*)d_in[3];
    const float* cb      = (const float*)d_in[4];
    const float* anchors = (const float*)d_in[5];
    const float* tv      = (const float*)d_in[6];
    const float* aw      = (const float*)d_in[7];
    float* out = (float*)d_out;

    // ws: Wh fp16 8.39MB | xh fp16 16.78MB | n2x[4096] | spart[1024] | scal[16]
    //     | P0 fp16 16.78MB   (~42 MB; K un-split, no P1)
    _Float16* Wh = (_Float16*)d_ws;
    _Float16* xh = Wh + (size_t)D_OUT * D_IN;
    float* n2x   = (float*)(xh + (size_t)B_ROWS * D_IN);
    float* spart = n2x + B_ROWS;
    float* scal  = spart + 1024;
    _Float16* P0 = (_Float16*)(scal + 16);

    k_prep<<<2049, 256, 0, stream>>>(x, wt, cw, cb, bias, anchors, xh, Wh, n2x, spart, scal);
    k_gemm<<<dim3(16, 16), 512, 0, stream>>>(xh, Wh, P0);
    k_mobius<<<B_ROWS, 256, 0, stream>>>(P0, P0, bias, anchors, tv, aw, n2x, spart, scal, 1, out);
}